// Round 5
// baseline (183.599 us; speedup 1.0000x reference)
//
#include <hip/hip_runtime.h>

// BoundarySeg: B=16, L=1024, H=768, MAX_SPAN_LEN=6 — all fp32
//
// R9 = DIAGNOSTIC ROUND (pre-committed in R2/R3). Same R7 kernel, body run
// TWICE inside one dispatch (idempotent stores, memory clobber between reps
// so loads re-issue). Dispatch dur ~2K > 60 us fills -> kernel enters the
// rocprof top-5 WITH its own counters. This settles, with direct evidence,
// whether the kernel is ~55 us (2x off roofline; read VALUBusy/Occupancy for
// the limiter) or ~28 us (at BW floor; harness fills dominate dur -> declare
// ROOFLINE next round, R8's 175.4 stands).
//   Ledger: R0=182.0(f59)->K~63 | R5=179.5(f65)->K~50 | R6=180.9(f65)->K~51
//           R8=175.4(f60)->K~55  — three different structures, same ~50-55.
//   Pre-committed reading:
//     hyp A: dispatch ~95-110 us, hbm ~2.5-3 TB/s -> not BW-bound;
//            VALUBusy>55% => VALU-interleave bound; Occupancy<10% => latency.
//     hyp B: dispatch ~55-62 us, hbm >=4.5 TB/s -> kernel at roofline.
//   Total dur this round is sacrificial (~205-225 expected).

#define LROWS 1024
#define HDIM  768
#define SPANW 6
#define HALO  (SPANW - 1)
#define RCHUNK 16
#define CHUNKS (LROWS / RCHUNK)      // 64
#define BLK   192                    // 3 waves; one f32x4 column per thread

typedef float f32x4 __attribute__((ext_vector_type(4)));

__global__ __launch_bounds__(BLK, 4) void boundary_seg_kernel(
    const float* __restrict__ span,   // (B, L, L, 1)
    const float* __restrict__ bound,  // (B, L, H)
    float* __restrict__ out)          // (B, L, 2H)
{
    __shared__ float sw[RCHUNK][8];   // [r] = {w0..w5, wsum, pad} — 512 B

    const int tid = threadIdx.x;

    // chunked XCD swizzle (gridDim.x = 1024, %8 == 0 -> bijective)
    const unsigned nwg = gridDim.x;
    const unsigned wg  = (nwg & 7u) ? blockIdx.x
                       : (blockIdx.x & 7u) * (nwg >> 3) + (blockIdx.x >> 3);

    const int b    = wg >> 6;                    // / CHUNKS
    const int j0   = (wg & (CHUNKS - 1)) * RCHUNK;
    const int bL   = b * LROWS;
    const int colf = tid << 2;                   // float col, 16 B/lane

#pragma unroll 1
    for (int rep = 0; rep < 2; ++rep) {          // DIAGNOSTIC: 2 identical reps
        // ---- preload the 21-row window for this column
        const float* bcol = bound + (size_t)bL * HDIM + colf;
        f32x4 h[RCHUNK + HALO];
#pragma unroll
        for (int r = 0; r < RCHUNK + HALO; ++r) {
            int gr = j0 + r;
            if (gr > LROWS - 1) gr = LROWS - 1;  // only last chunk clamps
            h[r] = *(const f32x4*)(bcol + (size_t)gr * HDIM);
        }

        // ---- stage span weights: one thread per row (wave 0 only)
        if (tid < RCHUNK) {
            const int j = j0 + tid;
            const float* sp = span + (size_t)(bL + j) * LROWS + j;
            float wsum = 0.f;
#pragma unroll
            for (int d = 0; d < SPANW; ++d) {
                const float v = (j + d < LROWS) ? sp[d] : 0.f;
                sw[tid][d] = v;
                wsum += v;
            }
            sw[tid][6] = wsum;
            sw[tid][7] = 0.f;
        }
        __syncthreads();

        // ---- 16 compute+store steps; w via conflict-free LDS broadcast
#pragma unroll
        for (int s = 0; s < RCHUNK; ++s) {
            const f32x4 w0 = *(const f32x4*)&sw[s][0];   // w0..w3
            const f32x4 w1 = *(const f32x4*)&sw[s][4];   // w4, w5, wsum, pad

            f32x4 acc = w0[0] * h[s]     + w0[1] * h[s + 1] + w0[2] * h[s + 2]
                      + w0[3] * h[s + 3] + w1[0] * h[s + 4] + w1[1] * h[s + 5];
            const f32x4 sec = h[s] * w1[2];

            float* orow = out + (size_t)(bL + j0 + s) * (2 * HDIM) + colf;
            *(f32x4*)orow          = acc;
            *(f32x4*)(orow + HDIM) = sec;
        }

        __syncthreads();                  // all reads of sw done before rep 2
        asm volatile("" ::: "memory");    // forbid cross-rep load CSE/hoist
    }
}

extern "C" void kernel_launch(void* const* d_in, const int* in_sizes, int n_in,
                              void* d_out, int out_size, void* d_ws, size_t ws_size,
                              hipStream_t stream) {
    const float* span  = (const float*)d_in[0];
    const float* bound = (const float*)d_in[1];
    float* out = (float*)d_out;

    const int B = in_sizes[1] / (LROWS * HDIM);       // 16 (element count)
    dim3 grid(B * CHUNKS), block(BLK);                // 1024 x 192
    hipLaunchKernelGGL(boundary_seg_kernel, grid, block, 0, stream,
                       span, bound, out);
}